// Round 9
// baseline (1957.145 us; speedup 1.0000x reference)
//
#include <hip/hip_runtime.h>
#include <hip/hip_bf16.h>
#include <cstdio>
#include <cstdint>

#define BS_   128
#define T_    128
#define A_    8
#define D_    128
#define H_    512
#define ROWS_ 1024           // BS*A
#define MTOT_ 131072         // BS*T*A
#define SLAB_ (ROWS_ * H_)   // one timestep slab (X or h), elements

typedef __hip_bfloat16 bf16;
typedef __attribute__((ext_vector_type(4))) float f32x4;
typedef __attribute__((ext_vector_type(8))) short s16x8;
typedef __attribute__((ext_vector_type(4))) short s16x4;

__device__ __forceinline__ void async_ld16(const void* g, const void* lds) {
  __builtin_amdgcn_global_load_lds((const __attribute__((address_space(1))) void*)g,
                                   (__attribute__((address_space(3))) void*)lds,
                                   16, 0, 0);
}
__device__ __forceinline__ s16x8 ldg8(const short* p) { return *(const s16x8*)p; }
__device__ __forceinline__ float sigm(float x) { return 1.f / (1.f + __expf(-x)); }
__device__ __forceinline__ float tanh_f(float x) {
  const float e = __expf(2.f * x);            // inf-safe
  return 1.f - 2.f / (e + 1.f);
}
__device__ __forceinline__ s16x8 cvt8(const float* p) {
  const float4 a = ((const float4*)p)[0];
  const float4 b = ((const float4*)p)[1];
  s16x8 r_;
  r_[0] = __builtin_bit_cast(short, __float2bfloat16(a.x));
  r_[1] = __builtin_bit_cast(short, __float2bfloat16(a.y));
  r_[2] = __builtin_bit_cast(short, __float2bfloat16(a.z));
  r_[3] = __builtin_bit_cast(short, __float2bfloat16(a.w));
  r_[4] = __builtin_bit_cast(short, __float2bfloat16(b.x));
  r_[5] = __builtin_bit_cast(short, __float2bfloat16(b.y));
  r_[6] = __builtin_bit_cast(short, __float2bfloat16(b.z));
  r_[7] = __builtin_bit_cast(short, __float2bfloat16(b.w));
  return r_;
}

// obs [b][t][a][d] fp32 -> obsB [t][b*8+a][d] bf16
__global__ __launch_bounds__(256)
void cvt_obs_kernel(const float* __restrict__ src, bf16* __restrict__ dst) {
  const int o = (blockIdx.x * 256 + threadIdx.x) << 2;
  const int d = o & 127, a = (o >> 7) & 7, t = (o >> 10) & 127, b = o >> 17;
  const float4 v = *(const float4*)(src + o);
  s16x4 pk;
  pk[0] = __builtin_bit_cast(short, __float2bfloat16(v.x));
  pk[1] = __builtin_bit_cast(short, __float2bfloat16(v.y));
  pk[2] = __builtin_bit_cast(short, __float2bfloat16(v.z));
  pk[3] = __builtin_bit_cast(short, __float2bfloat16(v.w));
  *(s16x4*)((short*)dst + ((((size_t)t << 10) + (b << 3) + a) << 7) + d) = pk;
}

__global__ __launch_bounds__(256)
void cvt_kernel(const float* __restrict__ src, bf16* __restrict__ dst) {
  const int i = (blockIdx.x * 256 + threadIdx.x) << 2;
  const float4 v = *(const float4*)(src + i);
  s16x4 o;
  o[0] = __builtin_bit_cast(short, __float2bfloat16(v.x));
  o[1] = __builtin_bit_cast(short, __float2bfloat16(v.y));
  o[2] = __builtin_bit_cast(short, __float2bfloat16(v.z));
  o[3] = __builtin_bit_cast(short, __float2bfloat16(v.w));
  *(s16x4*)((short*)dst + i) = o;
}

__global__ __launch_bounds__(256)
void bar_init_kernel(unsigned* __restrict__ bar) {
  const int i = threadIdx.x;
  bar[i] = 0u;          // 8 group counters (padded) ...
  bar[i + 256] = 0u;    // ... + roster[8] and slack
}

// ---------------------------------------------------------------------------
// X = relu(obsB @ W1^T + b1)
// ---------------------------------------------------------------------------
__global__ __launch_bounds__(256)
void xgemm_kernel(const bf16* __restrict__ Ag, const bf16* __restrict__ Wg,
                  const float* __restrict__ bias, bf16* __restrict__ Og) {
  const int bid = blockIdx.x;
  const int m0 = (bid >> 2) << 7;
  const int n0 = (bid & 3) << 7;
  const int tid = threadIdx.x;
  const int w = tid >> 6, lane = tid & 63;
  const int r = lane & 15, q = lane >> 4;
  const int wm = w & 1, wn = w >> 1;

  __shared__ short As[128 * 32];
  __shared__ short Bs[128 * 32];

  f32x4 acc[4][4];
  const f32x4 vz = {0.f, 0.f, 0.f, 0.f};
#pragma unroll
  for (int i = 0; i < 4; ++i)
#pragma unroll
    for (int j = 0; j < 4; ++j) acc[i][j] = vz;

  const int lrow = lane >> 2;
  const int kcol = (lane & 3) << 3;

  for (int kt = 0; kt < 4; ++kt) {          // K = 128
    __syncthreads();
    const int kbase = kt << 5;
#pragma unroll
    for (int jj = 0; jj < 2; ++jj) {
      const int c = (w << 1) + jj;
      const int m = (c << 4) + lrow;
      async_ld16(Ag + (size_t)(m0 + m) * D_ + kbase + kcol, &As[c << 9]);
      async_ld16(Wg + (size_t)(n0 + m) * D_ + kbase + kcol, &Bs[c << 9]);
    }
    __syncthreads();

    s16x8 af[4], bfr[4];
#pragma unroll
    for (int x = 0; x < 4; ++x) {
      af[x]  = *(const s16x8*)&As[((wm << 6) + (x << 4) + r) * 32 + (q << 3)];
      bfr[x] = *(const s16x8*)&Bs[((wn << 6) + (x << 4) + r) * 32 + (q << 3)];
    }
#pragma unroll
    for (int i = 0; i < 4; ++i)
#pragma unroll
      for (int j = 0; j < 4; ++j)
        acc[i][j] = __builtin_amdgcn_mfma_f32_16x16x32_bf16(af[i], bfr[j],
                                                            acc[i][j], 0, 0, 0);
  }

#pragma unroll
  for (int j = 0; j < 4; ++j) {
    const int gn = n0 + (wn << 6) + (j << 4) + r;
    const float bb = bias[gn];
#pragma unroll
    for (int i = 0; i < 4; ++i) {
      const int gmb = m0 + (wm << 6) + (i << 4) + (q << 2);
#pragma unroll
      for (int ii = 0; ii < 4; ++ii) {
        const int gm = gmb + ii;
        Og[(size_t)gm * H_ + gn] =
            __float2bfloat16(fmaxf(acc[i][j][ii] + bb, 0.f));
      }
    }
  }
}

// ---------------------------------------------------------------------------
// Persistent GRU scan, round-9: XCD-LOCAL groups (measured, not assumed).
//  * Each block reads its physical XCD via s_getreg(HW_REG_XCC_ID) and claims
//    slot = atomicAdd(roster[xcd]). Capacity bijection (256 blocks, 1/CU via
//    96KB LDS request, 32 CUs/XCD) => exactly 32 blocks per XCD. Block
//    (xcd, slot) owns rows xcd*128..+127, cols slot*16..+15.
//  * h exchange never leaves the XCD: PLAIN stores (write-allocate into the
//    shared per-XCD L2) + plain loads (L2 hits ~250cy). No sc-bit L3 round
//    trips, no L3 broadcast (r5-r8's shared floor). t-indexed slabs keep all
//    addresses virgin -> no stale L1/L2 lines possible.
//  * Barrier per XCD: one padded counter, 32 arrivals, agent-scope atomics
//    (the only remaining L3 traffic).
//  * ah full-16 burst (L2-fast); ax[0..7] for slab t+1 issued BETWEEN gh and
//    gates (in-order vmcnt: after all ah -> gh never waits on X; HBM latency
//    drains under gates+barrier); gi consumes post-arrive with ring reload.
// ---------------------------------------------------------------------------
__global__ __launch_bounds__(256, 1)
void scan_kernel(const float* __restrict__ Wih32, const float* __restrict__ Whh32,
                 const float* __restrict__ bih, const float* __restrict__ bhh,
                 const float* __restrict__ Wv, const short* __restrict__ Xs,
                 bf16* __restrict__ Hseq, float* __restrict__ Vp127,
                 unsigned* __restrict__ bar, unsigned* __restrict__ roster) {
  extern __shared__ short sm[];   // Wih lane-packed: 48 chunks x 512 shorts
  __shared__ unsigned grp[2];

  const int tid = threadIdx.x;
  const int w = tid >> 6, lane = tid & 63;
  const int r = lane & 15, q = lane >> 4;

  // ---- claim (xcd, slot) ----
  if (tid == 0) {
    unsigned xcd;
    asm volatile("s_getreg_b32 %0, hwreg(HW_REG_XCC_ID)" : "=s"(xcd));
    xcd &= 7u;
    grp[0] = xcd;
    grp[1] = atomicAdd(&roster[xcd], 1u) & 31u;
  }
  __syncthreads();
  const int rt = grp[0], jt = grp[1];
  const int j0 = jt << 4;
  const int rw = (rt << 7) + (w << 5);   // wave's 32 rows
  unsigned* barc = &bar[rt << 5];        // per-XCD counter, 128B padded

  // ---- Wih slice fp32 -> bf16, lane-packed into LDS (once) ----
#pragma unroll
  for (int i = 0; i < 12; ++i) {
    const int c = (i << 2) + w;          // chunk 0..47 = (g, kt)
    const int g = c >> 4, kt = c & 15;
    const s16x8 v = cvt8(Wih32 + (size_t)((g << 9) + j0 + r) * H_
                               + (kt << 5) + (q << 3));
    *(s16x8*)&sm[(c << 9) + (lane << 3)] = v;
  }

  // ---- Whh B-fragments fp32 -> bf16 registers (step-invariant) ----
  s16x8 whhf[3][16];
#pragma unroll
  for (int g = 0; g < 3; ++g)
#pragma unroll
    for (int kt = 0; kt < 16; ++kt)
      whhf[g][kt] = cvt8(Whh32 + (size_t)((g << 9) + j0 + r) * H_
                               + (kt << 5) + (q << 3));

  const int j = j0 + r;
  const float bR  = bih[j] + bhh[j];
  const float bZ  = bih[512 + j] + bhh[512 + j];
  const float bIN = bih[1024 + j];
  const float bHN = bhh[1024 + j];
  const float wvj = Wv[j];

  float hm[2][4] = {{0.f, 0.f, 0.f, 0.f}, {0.f, 0.f, 0.f, 0.f}};
  const f32x4 vz = {0.f, 0.f, 0.f, 0.f};

  const size_t aoff0 = (size_t)(rw + r) * H_ + (q << 3);
  const size_t aoff1 = aoff0 + (size_t)16 * H_;
  short* Hs = (short*)Hseq;

  __syncthreads();   // LDS staged

  // ---- prologue: gi(0) from X slab 0, ring-4 ----
  f32x4 gia[3][2];
#pragma unroll
  for (int g = 0; g < 3; ++g) { gia[g][0] = vz; gia[g][1] = vz; }
  {
    s16x8 ax0[4][2];
#pragma unroll
    for (int p = 0; p < 3; ++p) {
      ax0[p][0] = ldg8(Xs + aoff0 + (p << 5));
      ax0[p][1] = ldg8(Xs + aoff1 + (p << 5));
    }
#pragma unroll
    for (int kt = 0; kt < 16; ++kt) {
      const int cur = kt & 3;
      if (kt < 13) {
        const int np = (kt + 3) & 3;
        ax0[np][0] = ldg8(Xs + aoff0 + ((kt + 3) << 5));
        ax0[np][1] = ldg8(Xs + aoff1 + ((kt + 3) << 5));
      }
#pragma unroll
      for (int g = 0; g < 3; ++g) {
        const s16x8 b = *(const s16x8*)&sm[(((g << 4) + kt) << 9) + (lane << 3)];
        gia[g][0] = __builtin_amdgcn_mfma_f32_16x16x32_bf16(ax0[cur][0], b, gia[g][0], 0, 0, 0);
        gia[g][1] = __builtin_amdgcn_mfma_f32_16x16x32_bf16(ax0[cur][1], b, gia[g][1], 0, 0, 0);
      }
    }
  }

  for (int t = 0; t < T_; ++t) {
    // ---- wait (h slab t-1 complete within this XCD), then gh ----
    f32x4 gha[3][2];
#pragma unroll
    for (int g = 0; g < 3; ++g) { gha[g][0] = vz; gha[g][1] = vz; }
    if (t > 0) {
      if (tid == 0) {
        const unsigned tgt = (unsigned)t << 5;              // 32*t
        unsigned spins = 0;
        while (__hip_atomic_load(barc, __ATOMIC_RELAXED,
                                 __HIP_MEMORY_SCOPE_AGENT) < tgt) {
          __builtin_amdgcn_s_sleep(1);
          if (++spins > 8000000u) break;                    // dead-man valve
        }
      }
      __syncthreads();

      const short* hb = Hs + (size_t)(t - 1) * SLAB_;
      s16x8 ah[16][2];
#pragma unroll
      for (int kt = 0; kt < 16; ++kt) {        // full burst, L2 hits
        ah[kt][0] = ldg8(hb + aoff0 + (kt << 5));
        ah[kt][1] = ldg8(hb + aoff1 + (kt << 5));
      }
#pragma unroll
      for (int kt = 0; kt < 16; ++kt)
#pragma unroll
        for (int g = 0; g < 3; ++g) {
          gha[g][0] = __builtin_amdgcn_mfma_f32_16x16x32_bf16(ah[kt][0], whhf[g][kt], gha[g][0], 0, 0, 0);
          gha[g][1] = __builtin_amdgcn_mfma_f32_16x16x32_bf16(ah[kt][1], whhf[g][kt], gha[g][1], 0, 0, 0);
        }
    }

    const bool last = (t == T_ - 1);

    // ---- issue ax[0..7] for slab t+1 NOW (drains under gates+barrier) ----
    s16x8 ax[8][2];
    const short* xb = Xs + (size_t)(t + 1) * SLAB_;
    if (!last) {
#pragma unroll
      for (int p = 0; p < 8; ++p) {
        ax[p][0] = ldg8(xb + aoff0 + (p << 5));
        ax[p][1] = ldg8(xb + aoff1 + (p << 5));
      }
    }

    // ---- gates, h update (plain stores -> XCD-local L2) ----
    short* hrow = Hs + (size_t)t * SLAB_;
#pragma unroll
    for (int i = 0; i < 2; ++i)
#pragma unroll
      for (int ii = 0; ii < 4; ++ii) {
        const int row = rw + (i << 4) + (q << 2) + ii;
        const float rr = sigm(gia[0][i][ii] + gha[0][i][ii] + bR);
        const float zz = sigm(gia[1][i][ii] + gha[1][i][ii] + bZ);
        const float nn = tanh_f(gia[2][i][ii] + bIN + rr * (gha[2][i][ii] + bHN));
        const float hnew = (1.f - zz) * nn + zz * hm[i][ii];
        hm[i][ii] = hnew;
        if (!last) {
          // packed lane-pair plain store (cols j, j^1), write-allocate in L2
          const unsigned hv =
              (unsigned)(unsigned short)__builtin_bit_cast(unsigned short,
                                                           __float2bfloat16(hnew));
          const unsigned pv = (unsigned)__shfl_xor((int)hv, 1);
          if (!(r & 1))
            *(unsigned*)(hrow + (size_t)row * H_ + j0 + r) = hv | (pv << 16);
        } else {
          float vpv = wvj * hnew;
          vpv += __shfl_xor(vpv, 1);
          vpv += __shfl_xor(vpv, 2);
          vpv += __shfl_xor(vpv, 4);
          vpv += __shfl_xor(vpv, 8);       // sum 16 j-lanes
          if (r == 0) Vp127[(jt << 10) + row] = vpv;
        }
      }

    if (last) break;

    // ---- arrive: syncthreads drains h stores + ax loads (vmcnt0) ----
    __syncthreads();
    if (tid == 0) atomicAdd(barc, 1u);

    // ---- gi(t+1) in the arrive-shadow: consume ax, ring-reload 8..15 ----
#pragma unroll
    for (int g = 0; g < 3; ++g) { gia[g][0] = vz; gia[g][1] = vz; }
#pragma unroll
    for (int kt = 0; kt < 16; ++kt) {
      const int cur = kt & 7;
      const s16x8 a0 = ax[cur][0], a1 = ax[cur][1];
      if (kt < 8) {
        ax[cur][0] = ldg8(xb + aoff0 + ((kt + 8) << 5));
        ax[cur][1] = ldg8(xb + aoff1 + ((kt + 8) << 5));
      }
#pragma unroll
      for (int g = 0; g < 3; ++g) {
        const s16x8 b = *(const s16x8*)&sm[(((g << 4) + kt) << 9) + (lane << 3)];
        gia[g][0] = __builtin_amdgcn_mfma_f32_16x16x32_bf16(a0, b, gia[g][0], 0, 0, 0);
        gia[g][1] = __builtin_amdgcn_mfma_f32_16x16x32_bf16(a1, b, gia[g][1], 0, 0, 0);
      }
    }
  }
}

// ---------------------------------------------------------------------------
// out[b][t][a] = bv + Wv . h_t(row)  (h from Hseq for t<127, Vp127 for t=127)
// ---------------------------------------------------------------------------
__global__ __launch_bounds__(256)
void out_kernel(const bf16* __restrict__ Hseq, const float* __restrict__ Vp127,
                const float* __restrict__ Wv, const float* __restrict__ bv,
                float* __restrict__ out) {
  __shared__ float wvs[512];
  const int bid = blockIdx.x;           // 0..16383
  const int t = bid >> 7, rg = bid & 127;
  const int tid = threadIdx.x;
  const int r8 = tid >> 5, c = tid & 31;
  const int row = (rg << 3) + r8;
  if (tid < 128) *(float4*)&wvs[tid << 2] = *(const float4*)&Wv[tid << 2];
  __syncthreads();

  float s = 0.f;
  if (t < T_ - 1) {
    const short* hp = (const short*)Hseq + (size_t)t * SLAB_ + ((size_t)row << 9)
                    + (c << 4);
    const s16x8 h0 = ldg8(hp), h1 = ldg8(hp + 8);
    const float* wp = &wvs[c << 4];
#pragma unroll
    for (int k = 0; k < 8; ++k)
      s += wp[k] * __bfloat162float(__builtin_bit_cast(__hip_bfloat16, (unsigned short)h0[k]));
#pragma unroll
    for (int k = 0; k < 8; ++k)
      s += wp[8 + k] * __bfloat162float(__builtin_bit_cast(__hip_bfloat16, (unsigned short)h1[k]));
  } else {
    s = Vp127[(c << 10) + row];          // 32 partials, one per lane
  }
  s += __shfl_xor(s, 1);
  s += __shfl_xor(s, 2);
  s += __shfl_xor(s, 4);
  s += __shfl_xor(s, 8);
  s += __shfl_xor(s, 16);               // sum over 32 c-lanes
  if (c == 0)
    out[((row >> 3) << 10) + (t << 3) + (row & 7)] = s + bv[0];
}

extern "C" void kernel_launch(void* const* d_in, const int* in_sizes, int n_in,
                              void* d_out, int out_size, void* d_ws, size_t ws_size,
                              hipStream_t stream) {
  (void)in_sizes; (void)n_in; (void)out_size;
  const float* obs = (const float*)d_in[0];
  const float* W1  = (const float*)d_in[1];
  const float* b1  = (const float*)d_in[2];
  const float* Wih = (const float*)d_in[3];
  const float* bih = (const float*)d_in[4];
  const float* Whh = (const float*)d_in[5];
  const float* bhh = (const float*)d_in[6];
  const float* Wv  = (const float*)d_in[7];
  const float* bv  = (const float*)d_in[8];
  float* out = (float*)d_out;

  // ws (256 MiB): Hseq 127 slabs | X 128 slabs | spare 1 MiB
  //   obsB aliases Hseq slabs 0..31, W1B slab 32 (dead before h writes)
  char* ws = (char*)d_ws;
  bf16*  Hseq = (bf16*)ws;                                  // 127 MiB
  bf16*  obsB = Hseq;
  bf16*  W1B  = Hseq + (size_t)32 * SLAB_;
  bf16*  X    = (bf16*)(ws + (size_t)127 * SLAB_ * 2);      // 128 MiB
  char*  spare = ws + (size_t)255 * SLAB_ * 2;              // 1 MiB
  float* Vp127 = (float*)spare;                             // 128 KiB
  unsigned* bar = (unsigned*)(spare + 256 * 1024);          // 8 padded ctrs
  unsigned* roster = bar + 256;                             // roster[8]
  const size_t need = (size_t)256 * SLAB_ * 2;
  if (ws_size < need) {
    fprintf(stderr, "[kernel_launch] WS TOO SMALL: need %zu have %zu\n",
            need, ws_size);
    fflush(stderr);
  }

  hipFuncSetAttribute((const void*)scan_kernel,
                      hipFuncAttributeMaxDynamicSharedMemorySize, 98304);

  cvt_obs_kernel<<<16384, 256, 0, stream>>>(obs, obsB);
  cvt_kernel<<<64, 256, 0, stream>>>(W1, W1B);
  bar_init_kernel<<<1, 256, 0, stream>>>(bar);
  xgemm_kernel<<<4096, 256, 0, stream>>>(obsB, W1B, b1, X);
  // 96 KB dyn-LDS request (48 used) pins 1 block/CU -> 256 co-resident blocks
  scan_kernel<<<256, 256, 98304, stream>>>(Wih, Whh, bih, bhh, Wv, (const short*)X,
                                           Hseq, Vp127, bar, roster);
  out_kernel<<<16384, 256, 0, stream>>>(Hseq, Vp127, Wv, bv, out);
}